// Round 2
// baseline (1190.807 us; speedup 1.0000x reference)
//
#include <hip/hip_runtime.h>

#define D_MODEL 2048
#define D_INNER 4096
#define D_STATE 128
#define HEADDIM 64
#define NHEADS 64
#define CONV_DIM 4352
#define D_IN_PROJ 8512
#define BB 2
#define TSEQ 2048
#define BT (BB*TSEQ)
#define EPS_F 1e-5f

typedef __bf16 bf16x8 __attribute__((ext_vector_type(8)));
typedef float f32x4 __attribute__((ext_vector_type(4)));

__device__ __forceinline__ float bf2f(unsigned short u){
  unsigned int x = ((unsigned int)u) << 16;
  return __builtin_bit_cast(float, x);
}
__device__ __forceinline__ unsigned short f2bf(float f){
  unsigned int x = __builtin_bit_cast(unsigned int, f);
  x += 0x7fffu + ((x >> 16) & 1u);
  return (unsigned short)(x >> 16);
}

// fp32 -> bf16 cast, 8 elems/thread. n % 8 == 0.
__global__ __launch_bounds__(256) void cast_kernel(
    const float* __restrict__ in, unsigned short* __restrict__ out, int n)
{
  int i = (blockIdx.x * 256 + threadIdx.x) * 8;
  if (i >= n) return;
  float4 a = *(const float4*)&in[i];
  float4 b = *(const float4*)&in[i + 4];
  unsigned short o[8] = { f2bf(a.x), f2bf(a.y), f2bf(a.z), f2bf(a.w),
                          f2bf(b.x), f2bf(b.y), f2bf(b.z), f2bf(b.w) };
  *(uint4*)&out[i] = *(uint4*)o;
}

// C[m,n] = sum_k A[m,k]*B[n,k]; A: MxK bf16, B: NxK bf16 (both row-major).
// F32OUT: store fp32, else bf16. M%128==0, K%64==0; N ragged-guarded.
template <bool F32OUT>
__global__ __launch_bounds__(256) void gemm_tn_kernel(
    const unsigned short* __restrict__ A, const unsigned short* __restrict__ Bm,
    void* __restrict__ Cout, int M, int N, int K)
{
  __shared__ __align__(16) unsigned short As[128][72];  // +8 pad
  __shared__ __align__(16) unsigned short Bs[128][72];
  int tid = threadIdx.x;
  int m0 = blockIdx.y * 128, n0 = blockIdx.x * 128;
  int wave = tid >> 6, lane = tid & 63;
  int wm = wave >> 1, wn = wave & 1;           // 2x2 wave grid, 64x64 per wave
  int lm = lane & 15, kq = (lane >> 4) * 8;    // frag: m/n = lane&15, k = quad*8+j
  f32x4 acc[4][4] = {};

  int srow = tid >> 3, skc = (tid & 7) * 8;
  for (int k0 = 0; k0 < K; k0 += 64) {
#pragma unroll
    for (int ps = 0; ps < 4; ps++) {
      int row = ps * 32 + srow;
      *(uint4*)&As[row][skc] = *(const uint4*)&A[(size_t)(m0 + row) * K + k0 + skc];
      int br = n0 + row; if (br >= N) br = N - 1;   // clamp; masked at store
      *(uint4*)&Bs[row][skc] = *(const uint4*)&Bm[(size_t)br * K + k0 + skc];
    }
    __syncthreads();
#pragma unroll
    for (int kk = 0; kk < 64; kk += 32) {
      bf16x8 af[4], bfr[4];
#pragma unroll
      for (int i = 0; i < 4; i++) af[i]  = *(const bf16x8*)&As[wm * 64 + i * 16 + lm][kk + kq];
#pragma unroll
      for (int j = 0; j < 4; j++) bfr[j] = *(const bf16x8*)&Bs[wn * 64 + j * 16 + lm][kk + kq];
#pragma unroll
      for (int i = 0; i < 4; i++)
#pragma unroll
        for (int j = 0; j < 4; j++)
          acc[i][j] = __builtin_amdgcn_mfma_f32_16x16x32_bf16(af[i], bfr[j], acc[i][j], 0, 0, 0);
    }
    __syncthreads();
  }
  // C/D layout: col = lane&15 (n), row = (lane>>4)*4 + reg (m)
  int rq = lane >> 4;
#pragma unroll
  for (int i = 0; i < 4; i++) {
#pragma unroll
    for (int j = 0; j < 4; j++) {
      int col = n0 + wn * 64 + j * 16 + lm;
      if (col < N) {
        int mrow = m0 + wm * 64 + i * 16 + rq * 4;
#pragma unroll
        for (int r = 0; r < 4; r++) {
          if (F32OUT) ((float*)Cout)[(size_t)(mrow + r) * N + col] = acc[i][j][r];
          else ((unsigned short*)Cout)[(size_t)(mrow + r) * N + col] = f2bf(acc[i][j][r]);
        }
      }
    }
  }
}

// Depthwise causal conv (window 4) + bias + silu over zx[:, :, 4096:8448].
__global__ __launch_bounds__(256) void conv_silu_kernel(
    const unsigned short* __restrict__ zx, const float* __restrict__ conv_w,
    const float* __restrict__ conv_b,
    unsigned short* __restrict__ xconv, float* __restrict__ Bf, float* __restrict__ Cf)
{
  const int NG = CONV_DIM / 8;  // 544 groups of 8 channels
  int gid = blockIdx.x * 256 + threadIdx.x;
  if (gid >= BT * NG) return;
  int cg = gid % NG; int bt = gid / NG;
  int t = bt % TSEQ;
  int c0 = cg * 8;

  float wgt[8][4];
#pragma unroll
  for (int i = 0; i < 8; i++)
#pragma unroll
    for (int k = 0; k < 4; k++) wgt[i][k] = conv_w[(c0 + i) * 4 + k];

  float acc[8];
#pragma unroll
  for (int i = 0; i < 8; i++) acc[i] = conv_b[c0 + i];

#pragma unroll
  for (int k = 0; k < 4; k++) {
    int ts = t - 3 + k;
    if (ts < 0) continue;
    unsigned short xv[8];
    *(uint4*)xv = *(const uint4*)&zx[(size_t)(bt - 3 + k) * D_IN_PROJ + D_INNER + c0];
#pragma unroll
    for (int i = 0; i < 8; i++) acc[i] = fmaf(bf2f(xv[i]), wgt[i][k], acc[i]);
  }

  if (c0 < D_INNER) {
    unsigned short o[8];
#pragma unroll
    for (int i = 0; i < 8; i++) { float v = acc[i]; v = v / (1.f + expf(-v)); o[i] = f2bf(v); }
    *(uint4*)&xconv[(size_t)bt * D_INNER + c0] = *(uint4*)o;
  } else if (c0 < D_INNER + D_STATE) {
    int n = c0 - D_INNER;
#pragma unroll
    for (int i = 0; i < 8; i++) { float v = acc[i]; Bf[(size_t)bt * D_STATE + n + i] = v / (1.f + expf(-v)); }
  } else {
    int n = c0 - D_INNER - D_STATE;
#pragma unroll
    for (int i = 0; i < 8; i++) { float v = acc[i]; Cf[(size_t)bt * D_STATE + n + i] = v / (1.f + expf(-v)); }
  }
}

// dt = softplus(dt_raw + dt_bias); dA = exp(dt * -exp(A_log)); per (b,t,h)
__global__ __launch_bounds__(256) void dt_prep_kernel(
    const unsigned short* __restrict__ zx, const float* __restrict__ dt_bias,
    const float* __restrict__ A_log, float* __restrict__ dtv, float* __restrict__ dAv)
{
  int gid = blockIdx.x * 256 + threadIdx.x;  // bt*64 + h
  int h = gid & 63; int bt = gid >> 6;
  float x = bf2f(zx[(size_t)bt * D_IN_PROJ + D_INNER + CONV_DIM + h]) + dt_bias[h];
  float dt = (x > 20.f) ? x : log1pf(expf(x));
  float A = -expf(A_log[h]);
  dtv[gid] = dt;
  dAv[gid] = expf(dt * A);
}

// Selective scan. Block = (b, h, n-half): 64(p) x 64(n) fp32 state in regs.
// thread: p = tid>>2, owns n = half*64 + (tid&3)*16 + [0,16)
__global__ __launch_bounds__(256) void scan_kernel(
    const float* __restrict__ Bf, const float* __restrict__ Cf,
    const unsigned short* __restrict__ xconv,
    const float* __restrict__ dtv, const float* __restrict__ dAv,
    unsigned short* __restrict__ yp)
{
  const int TC = 8;
  __shared__ __align__(16) float Bs[TC][64];
  __shared__ __align__(16) float Cs[TC][64];
  __shared__ __align__(16) unsigned short xs[TC][64];
  __shared__ float dts[TC], dAs[TC];

  int blk = blockIdx.x;
  int nh = blk & 1; int bh = blk >> 1; int h = bh & 63; int b = bh >> 6;
  int tid = threadIdx.x; int p = tid >> 2; int c = tid & 3;
  size_t btbase = (size_t)b * TSEQ;

  float hst[16];
#pragma unroll
  for (int j = 0; j < 16; j++) hst[j] = 0.f;

  for (int t0 = 0; t0 < TSEQ; t0 += TC) {
    if (tid < 128) {
      int tt = tid >> 4, j = (tid & 15) * 4;
      *(float4*)&Bs[tt][j] = *(const float4*)&Bf[(btbase + t0 + tt) * D_STATE + nh * 64 + j];
    } else {
      int q = tid - 128; int tt = q >> 4, j = (q & 15) * 4;
      *(float4*)&Cs[tt][j] = *(const float4*)&Cf[(btbase + t0 + tt) * D_STATE + nh * 64 + j];
    }
    if (tid < 64) {
      int tt = tid >> 3, j = (tid & 7) * 8;
      *(uint4*)&xs[tt][j] = *(const uint4*)&xconv[(btbase + t0 + tt) * D_INNER + h * HEADDIM + j];
    }
    if (tid >= 224 && tid < 232) dts[tid - 224] = dtv[(btbase + t0 + tid - 224) * NHEADS + h];
    else if (tid >= 232 && tid < 240) dAs[tid - 232] = dAv[(btbase + t0 + tid - 232) * NHEADS + h];
    __syncthreads();
#pragma unroll
    for (int tt = 0; tt < TC; tt++) {
      float dA = dAs[tt];
      float dtval = dts[tt];
      float xv = bf2f(xs[tt][p]);
      float dtx = dtval * xv;
      float acc = 0.f;
#pragma unroll
      for (int j = 0; j < 16; j++) {
        float hv = hst[j] * dA + dtx * Bs[tt][c * 16 + j];
        hst[j] = hv;
        acc = fmaf(hv, Cs[tt][c * 16 + j], acc);
      }
      acc += __shfl_xor(acc, 1);
      acc += __shfl_xor(acc, 2);
      if (c == 0)
        yp[((size_t)nh * BT + btbase + t0 + tt) * D_INNER + h * HEADDIM + p] = f2bf(acc);
    }
    __syncthreads();
  }
}

// y = (yp0 + yp1 + Dskip[h]*x_ssm) * silu(z); rmsnorm over 4096; write bf16.
__global__ __launch_bounds__(256) void gate_norm_kernel(
    const unsigned short* __restrict__ yp, const unsigned short* __restrict__ xconv,
    const unsigned short* __restrict__ zx, const float* __restrict__ Dskip,
    const float* __restrict__ norm_w, unsigned short* __restrict__ ybf)
{
  int row = blockIdx.x; int tid = threadIdx.x;
  int c0 = tid * 16;
  float dsk = Dskip[tid >> 2];   // 16 channels per thread stay inside one head
  unsigned short y0[16], y1[16], xv[16], zv[16];
  const size_t base = (size_t)row * D_INNER + c0;
  *(uint4*)&y0[0] = *(const uint4*)&yp[base];
  *(uint4*)&y0[8] = *(const uint4*)&yp[base + 8];
  *(uint4*)&y1[0] = *(const uint4*)&yp[(size_t)BT * D_INNER + base];
  *(uint4*)&y1[8] = *(const uint4*)&yp[(size_t)BT * D_INNER + base + 8];
  *(uint4*)&xv[0] = *(const uint4*)&xconv[base];
  *(uint4*)&xv[8] = *(const uint4*)&xconv[base + 8];
  const size_t zbase = (size_t)row * D_IN_PROJ + c0;
  *(uint4*)&zv[0] = *(const uint4*)&zx[zbase];
  *(uint4*)&zv[8] = *(const uint4*)&zx[zbase + 8];

  float g[16]; float ss = 0.f;
#pragma unroll
  for (int i = 0; i < 16; i++) {
    float y = bf2f(y0[i]) + bf2f(y1[i]) + dsk * bf2f(xv[i]);
    float z = bf2f(zv[i]);
    float gate = z / (1.f + expf(-z));
    float gv = y * gate;
    g[i] = gv; ss += gv * gv;
  }
#pragma unroll
  for (int o = 32; o >= 1; o >>= 1) ss += __shfl_xor(ss, o);
  __shared__ float red[4]; __shared__ float stot;
  if ((tid & 63) == 0) red[tid >> 6] = ss;
  __syncthreads();
  if (tid == 0) stot = red[0] + red[1] + red[2] + red[3];
  __syncthreads();
  float scale = rsqrtf(stot * (1.f / D_INNER) + EPS_F);
  unsigned short o16[16];
#pragma unroll
  for (int i = 0; i < 16; i++) o16[i] = f2bf(g[i] * scale * norm_w[c0 + i]);
  *(uint4*)&ybf[base] = *(uint4*)&o16[0];
  *(uint4*)&ybf[base + 8] = *(uint4*)&o16[8];
}

extern "C" void kernel_launch(void* const* d_in, const int* in_sizes, int n_in,
                              void* d_out, int out_size, void* d_ws, size_t ws_size,
                              hipStream_t stream) {
  (void)in_sizes; (void)n_in; (void)out_size; (void)ws_size;
  const float* x          = (const float*)d_in[0];
  // d_in[1]=cos, d_in[2]=sin: unused by reference
  const float* in_proj_w  = (const float*)d_in[3];
  const float* conv_w     = (const float*)d_in[4];
  const float* conv_b     = (const float*)d_in[5];
  const float* dt_bias    = (const float*)d_in[6];
  const float* A_log      = (const float*)d_in[7];
  const float* Dskip      = (const float*)d_in[8];
  const float* norm_w     = (const float*)d_in[9];
  const float* out_proj_w = (const float*)d_in[10];
  float* out = (float*)d_out;

  // Workspace layout (overlays are strictly write-after-last-read):
  //   zx    : BT*8512 bf16 = 69,730,304 B
  //   xconv : BT*4096 bf16 = 33,554,432 B
  //   Bf/Cf : BT*128 f32 x2 =  4,194,304 B
  //   dt/dA : BT*64  f32 x2 =  2,097,152 B
  //   Y     : max(yp 67,108,864 ; xb 16,777,216 ; wob 16,777,216) = 67,108,864 B
  //           (xb used only pre-scan; wob written post-gate_norm when yp is dead)
  //   W     : max(wib 34,865,152 ; ybf 33,554,432) = 34,865,152 B
  // total: 211,550,208 B
  char* w = (char*)d_ws;
  unsigned short* zx    = (unsigned short*)(w);
  unsigned short* xconv = (unsigned short*)(w + 69730304);
  float* Bf  = (float*)(w + 103284736);
  float* Cf  = (float*)(w + 105381888);
  float* dtv = (float*)(w + 107479040);
  float* dAv = (float*)(w + 108527616);
  char* Y = w + 109576192;
  char* W = w + 176685056;
  unsigned short* yp  = (unsigned short*)Y;
  unsigned short* xb  = (unsigned short*)Y;           // overlay (pre-scan only)
  unsigned short* wob = (unsigned short*)Y;           // overlay (post-gate_norm)
  unsigned short* wib = (unsigned short*)W;
  unsigned short* ybf = (unsigned short*)W;           // overlay (post-GEMM1)

  // 0) casts fp32 -> bf16
  cast_kernel<<<(BT * D_MODEL / 8 + 255) / 256, 256, 0, stream>>>(x, xb, BT * D_MODEL);
  cast_kernel<<<(D_IN_PROJ * D_MODEL / 8 + 255) / 256, 256, 0, stream>>>(in_proj_w, wib, D_IN_PROJ * D_MODEL);
  // 1) zxbcdt = x @ in_proj_w^T   (M=4096, N=8512, K=2048)
  gemm_tn_kernel<false><<<dim3((D_IN_PROJ + 127) / 128, BT / 128), 256, 0, stream>>>(
      xb, wib, zx, BT, D_IN_PROJ, D_MODEL);
  // 2) conv + silu
  conv_silu_kernel<<<(BT * (CONV_DIM / 8) + 255) / 256, 256, 0, stream>>>(
      zx, conv_w, conv_b, xconv, Bf, Cf);
  // 3) dt / dA
  dt_prep_kernel<<<(BT * NHEADS) / 256, 256, 0, stream>>>(zx, dt_bias, A_log, dtv, dAv);
  // 4) selective scan (2 n-halves per (b,h))
  scan_kernel<<<BB * NHEADS * 2, 256, 0, stream>>>(Bf, Cf, xconv, dtv, dAv, yp);
  // 5) gate + rmsnorm
  gate_norm_kernel<<<BT, 256, 0, stream>>>(yp, xconv, zx, Dskip, norm_w, ybf);
  // 6) out = y @ out_proj_w^T   (M=4096, N=2048, K=4096), fp32 out
  cast_kernel<<<(D_MODEL * D_INNER / 8 + 255) / 256, 256, 0, stream>>>(out_proj_w, wob, D_MODEL * D_INNER);
  gemm_tn_kernel<true><<<dim3(D_MODEL / 128, BT / 128), 256, 0, stream>>>(
      ybf, wob, out, BT, D_MODEL, D_INNER);
}

// Round 3
// 670.687 us; speedup vs baseline: 1.7755x; 1.7755x over previous
//
#include <hip/hip_runtime.h>

#define D_MODEL 2048
#define D_INNER 4096
#define D_STATE 128
#define HEADDIM 64
#define NHEADS 64
#define CONV_DIM 4352
#define D_IN_PROJ 8512
#define BB 2
#define TSEQ 2048
#define BT (BB*TSEQ)
#define NCHUNK 32
#define LCH 64
#define EPS_F 1e-5f

typedef __bf16 bf16x8 __attribute__((ext_vector_type(8)));
typedef float f32x4 __attribute__((ext_vector_type(4)));

__device__ __forceinline__ float bf2f(unsigned short u){
  unsigned int x = ((unsigned int)u) << 16;
  return __builtin_bit_cast(float, x);
}
__device__ __forceinline__ unsigned short f2bf(float f){
  unsigned int x = __builtin_bit_cast(unsigned int, f);
  x += 0x7fffu + ((x >> 16) & 1u);
  return (unsigned short)(x >> 16);
}

// fp32 -> bf16 cast, 8 elems/thread. n % 8 == 0.
__global__ __launch_bounds__(256) void cast_kernel(
    const float* __restrict__ in, unsigned short* __restrict__ out, int n)
{
  int i = (blockIdx.x * 256 + threadIdx.x) * 8;
  if (i >= n) return;
  float4 a = *(const float4*)&in[i];
  float4 b = *(const float4*)&in[i + 4];
  unsigned short o[8] = { f2bf(a.x), f2bf(a.y), f2bf(a.z), f2bf(a.w),
                          f2bf(b.x), f2bf(b.y), f2bf(b.z), f2bf(b.w) };
  *(uint4*)&out[i] = *(uint4*)o;
}

// C[m,n] = sum_k A[m,k]*B[n,k]; A: MxK bf16, B: NxK bf16 (row-major).
template <bool F32OUT>
__global__ __launch_bounds__(256) void gemm_tn_kernel(
    const unsigned short* __restrict__ A, const unsigned short* __restrict__ Bm,
    void* __restrict__ Cout, int M, int N, int K)
{
  __shared__ __align__(16) unsigned short As[128][72];
  __shared__ __align__(16) unsigned short Bs[128][72];
  int tid = threadIdx.x;
  int m0 = blockIdx.y * 128, n0 = blockIdx.x * 128;
  int wave = tid >> 6, lane = tid & 63;
  int wm = wave >> 1, wn = wave & 1;
  int lm = lane & 15, kq = (lane >> 4) * 8;
  f32x4 acc[4][4] = {};

  int srow = tid >> 3, skc = (tid & 7) * 8;
  for (int k0 = 0; k0 < K; k0 += 64) {
#pragma unroll
    for (int ps = 0; ps < 4; ps++) {
      int row = ps * 32 + srow;
      *(uint4*)&As[row][skc] = *(const uint4*)&A[(size_t)(m0 + row) * K + k0 + skc];
      int br = n0 + row; if (br >= N) br = N - 1;
      *(uint4*)&Bs[row][skc] = *(const uint4*)&Bm[(size_t)br * K + k0 + skc];
    }
    __syncthreads();
#pragma unroll
    for (int kk = 0; kk < 64; kk += 32) {
      bf16x8 af[4], bfr[4];
#pragma unroll
      for (int i = 0; i < 4; i++) af[i]  = *(const bf16x8*)&As[wm * 64 + i * 16 + lm][kk + kq];
#pragma unroll
      for (int j = 0; j < 4; j++) bfr[j] = *(const bf16x8*)&Bs[wn * 64 + j * 16 + lm][kk + kq];
#pragma unroll
      for (int i = 0; i < 4; i++)
#pragma unroll
        for (int j = 0; j < 4; j++)
          acc[i][j] = __builtin_amdgcn_mfma_f32_16x16x32_bf16(af[i], bfr[j], acc[i][j], 0, 0, 0);
    }
    __syncthreads();
  }
  int rq = lane >> 4;
#pragma unroll
  for (int i = 0; i < 4; i++) {
#pragma unroll
    for (int j = 0; j < 4; j++) {
      int col = n0 + wn * 64 + j * 16 + lm;
      if (col < N) {
        int mrow = m0 + wm * 64 + i * 16 + rq * 4;
#pragma unroll
        for (int r = 0; r < 4; r++) {
          if (F32OUT) ((float*)Cout)[(size_t)(mrow + r) * N + col] = acc[i][j][r];
          else ((unsigned short*)Cout)[(size_t)(mrow + r) * N + col] = f2bf(acc[i][j][r]);
        }
      }
    }
  }
}

// Depthwise causal conv (window 4) + bias + silu.
__global__ __launch_bounds__(256) void conv_silu_kernel(
    const unsigned short* __restrict__ zx, const float* __restrict__ conv_w,
    const float* __restrict__ conv_b,
    unsigned short* __restrict__ xconv, float* __restrict__ Bf, float* __restrict__ Cf)
{
  const int NG = CONV_DIM / 8;
  int gid = blockIdx.x * 256 + threadIdx.x;
  if (gid >= BT * NG) return;
  int cg = gid % NG; int bt = gid / NG;
  int t = bt % TSEQ;
  int c0 = cg * 8;

  float wgt[8][4];
#pragma unroll
  for (int i = 0; i < 8; i++)
#pragma unroll
    for (int k = 0; k < 4; k++) wgt[i][k] = conv_w[(c0 + i) * 4 + k];

  float acc[8];
#pragma unroll
  for (int i = 0; i < 8; i++) acc[i] = conv_b[c0 + i];

#pragma unroll
  for (int k = 0; k < 4; k++) {
    int ts = t - 3 + k;
    if (ts < 0) continue;
    unsigned short xv[8];
    *(uint4*)xv = *(const uint4*)&zx[(size_t)(bt - 3 + k) * D_IN_PROJ + D_INNER + c0];
#pragma unroll
    for (int i = 0; i < 8; i++) acc[i] = fmaf(bf2f(xv[i]), wgt[i][k], acc[i]);
  }

  if (c0 < D_INNER) {
    unsigned short o[8];
#pragma unroll
    for (int i = 0; i < 8; i++) { float v = acc[i]; v = v / (1.f + expf(-v)); o[i] = f2bf(v); }
    *(uint4*)&xconv[(size_t)bt * D_INNER + c0] = *(uint4*)o;
  } else if (c0 < D_INNER + D_STATE) {
    int n = c0 - D_INNER;
#pragma unroll
    for (int i = 0; i < 8; i++) { float v = acc[i]; Bf[(size_t)bt * D_STATE + n + i] = v / (1.f + expf(-v)); }
  } else {
    int n = c0 - D_INNER - D_STATE;
#pragma unroll
    for (int i = 0; i < 8; i++) { float v = acc[i]; Cf[(size_t)bt * D_STATE + n + i] = v / (1.f + expf(-v)); }
  }
}

// dt = softplus(dt_raw + dt_bias); la = dt * A  (A = -exp(A_log)); per (b,t,h)
__global__ __launch_bounds__(256) void dt_prep_kernel(
    const unsigned short* __restrict__ zx, const float* __restrict__ dt_bias,
    const float* __restrict__ A_log, float* __restrict__ dtv, float* __restrict__ lav)
{
  int gid = blockIdx.x * 256 + threadIdx.x;  // bt*64 + h
  int h = gid & 63; int bt = gid >> 6;
  float x = bf2f(zx[(size_t)bt * D_IN_PROJ + D_INNER + CONV_DIM + h]) + dt_bias[h];
  float dt = (x > 20.f) ? x : log1pf(expf(x));
  float A = -expf(A_log[h]);
  dtv[gid] = dt;
  lav[gid] = dt * A;
}

// Inclusive cumsum of la within each chunk. One wave per (b,chunk,h).
// ca layout: [(b*32+c)*64 + h][64]
__global__ __launch_bounds__(256) void cumsum_kernel(
    const float* __restrict__ lav, float* __restrict__ ca)
{
  int g = blockIdx.x * 4 + (threadIdx.x >> 6);   // g = (b*32+c)*64 + h
  int lane = threadIdx.x & 63;
  int h = g & 63; int cb = g >> 6;               // cb = b*32+c;  bt = cb*64 + i
  float v = lav[((size_t)cb * 64 + lane) * 64 + h];
#pragma unroll
  for (int off = 1; off < 64; off <<= 1) {
    float t = __shfl_up(v, off);
    if (lane >= off) v += t;
  }
  ca[(size_t)g * 64 + lane] = v;
}

// G[i,j] = sum_n C[i,n]*B[j,n] per (b,chunk). Shared across heads (NGROUPS=1).
__global__ __launch_bounds__(256) void chunk_g_kernel(
    const float* __restrict__ Bf, const float* __restrict__ Cf,
    unsigned short* __restrict__ G)
{
  __shared__ __align__(16) unsigned short Cs[64][136];
  __shared__ __align__(16) unsigned short Bs2[64][136];
  int tid = threadIdx.x; int cb = blockIdx.x;
  size_t bt0 = (size_t)cb * 64;
  int row = tid >> 2, seg = (tid & 3) * 32;
#pragma unroll
  for (int u = 0; u < 32; u += 8) {
    float4 a = *(const float4*)&Cf[(bt0 + row) * 128 + seg + u];
    float4 b = *(const float4*)&Cf[(bt0 + row) * 128 + seg + u + 4];
    unsigned short o[8] = { f2bf(a.x), f2bf(a.y), f2bf(a.z), f2bf(a.w),
                            f2bf(b.x), f2bf(b.y), f2bf(b.z), f2bf(b.w) };
    *(uint4*)&Cs[row][seg + u] = *(uint4*)o;
    float4 c = *(const float4*)&Bf[(bt0 + row) * 128 + seg + u];
    float4 d = *(const float4*)&Bf[(bt0 + row) * 128 + seg + u + 4];
    unsigned short o2[8] = { f2bf(c.x), f2bf(c.y), f2bf(c.z), f2bf(c.w),
                             f2bf(d.x), f2bf(d.y), f2bf(d.z), f2bf(d.w) };
    *(uint4*)&Bs2[row][seg + u] = *(uint4*)o2;
  }
  __syncthreads();
  int wave = tid >> 6, lane = tid & 63, lm = lane & 15, kq = (lane >> 4) * 8, rq = lane >> 4;
  f32x4 acc[4] = {};
#pragma unroll
  for (int ks = 0; ks < 4; ks++) {
    bf16x8 af = *(const bf16x8*)&Cs[wave * 16 + lm][ks * 32 + kq];
#pragma unroll
    for (int jt = 0; jt < 4; jt++) {
      bf16x8 bb = *(const bf16x8*)&Bs2[jt * 16 + lm][ks * 32 + kq];
      acc[jt] = __builtin_amdgcn_mfma_f32_16x16x32_bf16(af, bb, acc[jt], 0, 0, 0);
    }
  }
#pragma unroll
  for (int jt = 0; jt < 4; jt++)
#pragma unroll
    for (int r = 0; r < 4; r++) {
      int i = wave * 16 + rq * 4 + r, j = jt * 16 + lm;
      G[(size_t)cb * 4096 + i * 64 + j] = f2bf(acc[jt][r]);
    }
}

// S[p,n] = sum_j exp(ca63-ca[j])*dt[j]*x[j,p] * B[j,n], per (b,h,chunk).
__global__ __launch_bounds__(256) void chunk_state_kernel(
    const float* __restrict__ Bf, const unsigned short* __restrict__ xconv,
    const float* __restrict__ dtv, const float* __restrict__ ca,
    unsigned short* __restrict__ S)
{
  __shared__ __align__(16) unsigned short Ax[64][72];
  __shared__ __align__(16) unsigned short Bn[128][72];
  int tid = threadIdx.x;
  int c = blockIdx.x & 31, h = (blockIdx.x >> 5) & 63, b = blockIdx.x >> 11;
  int cb = b * 32 + c;
  size_t bt0 = (size_t)cb * 64;
  const float* cag = &ca[((size_t)cb * 64 + h) * 64];
  float ca63 = cag[63];
  {
    int j = tid >> 2, pseg = (tid & 3) * 16;
    float wj = expf(ca63 - cag[j]) * dtv[(bt0 + j) * 64 + h];
    unsigned short xv[16];
    *(uint4*)&xv[0] = *(const uint4*)&xconv[(bt0 + j) * 4096 + h * 64 + pseg];
    *(uint4*)&xv[8] = *(const uint4*)&xconv[(bt0 + j) * 4096 + h * 64 + pseg + 8];
#pragma unroll
    for (int q = 0; q < 16; q++) Ax[pseg + q][j] = f2bf(wj * bf2f(xv[q]));
  }
  {
    int j = tid >> 2, nseg = (tid & 3) * 32;
#pragma unroll
    for (int u = 0; u < 32; u += 4) {
      float4 bv = *(const float4*)&Bf[(bt0 + j) * 128 + nseg + u];
      Bn[nseg + u][j] = f2bf(bv.x); Bn[nseg + u + 1][j] = f2bf(bv.y);
      Bn[nseg + u + 2][j] = f2bf(bv.z); Bn[nseg + u + 3][j] = f2bf(bv.w);
    }
  }
  __syncthreads();
  int wave = tid >> 6, lane = tid & 63, lm = lane & 15, kq = (lane >> 4) * 8, rq = lane >> 4;
  f32x4 acc[8] = {};
#pragma unroll
  for (int ks = 0; ks < 2; ks++) {
    bf16x8 af = *(const bf16x8*)&Ax[wave * 16 + lm][ks * 32 + kq];
#pragma unroll
    for (int nt = 0; nt < 8; nt++) {
      bf16x8 bb = *(const bf16x8*)&Bn[nt * 16 + lm][ks * 32 + kq];
      acc[nt] = __builtin_amdgcn_mfma_f32_16x16x32_bf16(af, bb, acc[nt], 0, 0, 0);
    }
  }
  size_t sbase = ((size_t)(b * 64 + h) * 32 + c) * 8192;
#pragma unroll
  for (int nt = 0; nt < 8; nt++)
#pragma unroll
    for (int r = 0; r < 4; r++) {
      int p = wave * 16 + rq * 4 + r, n = nt * 16 + lm;
      S[sbase + p * 128 + n] = f2bf(acc[nt][r]);
    }
}

// Sequential pass over 32 chunks: read S[c], write h_in[c] (in place), update
// h = exp(ca63_c)*h + S[c]. Per (b,h); thread owns 4 state elems.
__global__ __launch_bounds__(256) void state_pass_kernel(
    unsigned short* __restrict__ Shin, const float* __restrict__ ca)
{
  int part = blockIdx.x & 7, bh = blockIdx.x >> 3;   // bh = b*64+h
  int h = bh & 63, b = bh >> 6;
  int e0 = part * 1024 + threadIdx.x * 4;
  size_t base = (size_t)bh * 32 * 8192;
  float hc[4] = {0.f, 0.f, 0.f, 0.f};
  for (int c = 0; c < 32; c++) {
    float sc = expf(ca[(((size_t)(b * 32 + c)) * 64 + h) * 64 + 63]);
    size_t off = base + (size_t)c * 8192 + e0;
    uint2 sv = *(uint2*)&Shin[off];
    unsigned short* sp = (unsigned short*)&sv;
    unsigned short ho[4];
#pragma unroll
    for (int q = 0; q < 4; q++) ho[q] = f2bf(hc[q]);
    *(uint2*)&Shin[off] = *(uint2*)ho;
#pragma unroll
    for (int q = 0; q < 4; q++) hc[q] = sc * hc[q] + bf2f(sp[q]);
  }
}

// y[i,p] = sum_j M[i,j]*dtx[j,p] + sum_n exp(ca[i])*C[i,n]*hin[p,n] + Dskip*x
// as one K=192 MFMA per (b,h,chunk). M[i,j] = G[i,j]*exp(ca[i]-ca[j]) (j<=i).
__global__ __launch_bounds__(256) void chunk_y_kernel(
    const unsigned short* __restrict__ G, const float* __restrict__ Cf,
    const unsigned short* __restrict__ xconv, const float* __restrict__ dtv,
    const float* __restrict__ ca, const unsigned short* __restrict__ hin,
    const float* __restrict__ Dskip, unsigned short* __restrict__ yp)
{
  __shared__ __align__(16) unsigned short Aop[64][200];
  __shared__ __align__(16) unsigned short Bop[64][200];
  __shared__ __align__(16) unsigned short xs[64][72];
  __shared__ float cas[64]; __shared__ float dts[64];
  int tid = threadIdx.x;
  int c = blockIdx.x & 31, h = (blockIdx.x >> 5) & 63, b = blockIdx.x >> 11;
  int cb = b * 32 + c;
  size_t bt0 = (size_t)cb * 64;
  if (tid < 64) {
    cas[tid] = ca[((size_t)cb * 64 + h) * 64 + tid];
    dts[tid] = dtv[(bt0 + tid) * 64 + h];
  }
  __syncthreads();
  {
    int i = tid >> 2, jseg = (tid & 3) * 16;
    float cai = cas[i];
    unsigned short gv[16];
    *(uint4*)&gv[0] = *(const uint4*)&G[(size_t)cb * 4096 + i * 64 + jseg];
    *(uint4*)&gv[8] = *(const uint4*)&G[(size_t)cb * 4096 + i * 64 + jseg + 8];
    unsigned short o[16];
#pragma unroll
    for (int q = 0; q < 16; q++) {
      int j = jseg + q;
      float m = (j <= i) ? bf2f(gv[q]) * expf(cai - cas[j]) : 0.f;
      o[q] = f2bf(m);
    }
    *(uint4*)&Aop[i][jseg] = *(uint4*)&o[0];
    *(uint4*)&Aop[i][jseg + 8] = *(uint4*)&o[8];
  }
  {
    int i = tid >> 2, nseg = (tid & 3) * 32;
    float sci = expf(cas[i]);
#pragma unroll
    for (int u = 0; u < 32; u += 8) {
      float4 a = *(const float4*)&Cf[(bt0 + i) * 128 + nseg + u];
      float4 bq = *(const float4*)&Cf[(bt0 + i) * 128 + nseg + u + 4];
      unsigned short o[8] = { f2bf(sci * a.x), f2bf(sci * a.y), f2bf(sci * a.z), f2bf(sci * a.w),
                              f2bf(sci * bq.x), f2bf(sci * bq.y), f2bf(sci * bq.z), f2bf(sci * bq.w) };
      *(uint4*)&Aop[i][64 + nseg + u] = *(uint4*)o;
    }
  }
  {
    int j = tid >> 2, pseg = (tid & 3) * 16;
    float dtj = dts[j];
    unsigned short xv[16];
    *(uint4*)&xv[0] = *(const uint4*)&xconv[(bt0 + j) * 4096 + h * 64 + pseg];
    *(uint4*)&xv[8] = *(const uint4*)&xconv[(bt0 + j) * 4096 + h * 64 + pseg + 8];
#pragma unroll
    for (int q = 0; q < 16; q++) Bop[pseg + q][j] = f2bf(dtj * bf2f(xv[q]));
    *(uint4*)&xs[j][pseg] = *(uint4*)&xv[0];
    *(uint4*)&xs[j][pseg + 8] = *(uint4*)&xv[8];
  }
  {
    int p = tid >> 2, nseg = (tid & 3) * 32;
    size_t hb = ((size_t)(b * 64 + h) * 32 + c) * 8192 + p * 128 + nseg;
#pragma unroll
    for (int u = 0; u < 32; u += 8)
      *(uint4*)&Bop[p][64 + nseg + u] = *(const uint4*)&hin[hb + u];
  }
  __syncthreads();
  int wave = tid >> 6, lane = tid & 63, lm = lane & 15, kq = (lane >> 4) * 8, rq = lane >> 4;
  f32x4 acc[4] = {};
#pragma unroll
  for (int ks = 0; ks < 6; ks++) {
    bf16x8 af = *(const bf16x8*)&Aop[wave * 16 + lm][ks * 32 + kq];
#pragma unroll
    for (int pt = 0; pt < 4; pt++) {
      bf16x8 bb = *(const bf16x8*)&Bop[pt * 16 + lm][ks * 32 + kq];
      acc[pt] = __builtin_amdgcn_mfma_f32_16x16x32_bf16(af, bb, acc[pt], 0, 0, 0);
    }
  }
  float dsk = Dskip[h];
#pragma unroll
  for (int pt = 0; pt < 4; pt++)
#pragma unroll
    for (int r = 0; r < 4; r++) {
      int i = wave * 16 + rq * 4 + r, p = pt * 16 + lm;
      float y = acc[pt][r] + dsk * bf2f(xs[i][p]);
      yp[(bt0 + i) * 4096 + h * 64 + p] = f2bf(y);
    }
}

// y already includes Dskip*x. gate with silu(z), rmsnorm, write bf16.
__global__ __launch_bounds__(256) void gate_norm_kernel(
    const unsigned short* __restrict__ yp, const unsigned short* __restrict__ zx,
    const float* __restrict__ norm_w, unsigned short* __restrict__ ybf)
{
  int row = blockIdx.x; int tid = threadIdx.x;
  int c0 = tid * 16;
  unsigned short y0[16], zv[16];
  const size_t base = (size_t)row * D_INNER + c0;
  *(uint4*)&y0[0] = *(const uint4*)&yp[base];
  *(uint4*)&y0[8] = *(const uint4*)&yp[base + 8];
  const size_t zbase = (size_t)row * D_IN_PROJ + c0;
  *(uint4*)&zv[0] = *(const uint4*)&zx[zbase];
  *(uint4*)&zv[8] = *(const uint4*)&zx[zbase + 8];

  float g[16]; float ss = 0.f;
#pragma unroll
  for (int i = 0; i < 16; i++) {
    float y = bf2f(y0[i]);
    float z = bf2f(zv[i]);
    float gate = z / (1.f + expf(-z));
    float gv = y * gate;
    g[i] = gv; ss += gv * gv;
  }
#pragma unroll
  for (int o = 32; o >= 1; o >>= 1) ss += __shfl_xor(ss, o);
  __shared__ float red[4]; __shared__ float stot;
  if ((tid & 63) == 0) red[tid >> 6] = ss;
  __syncthreads();
  if (tid == 0) stot = red[0] + red[1] + red[2] + red[3];
  __syncthreads();
  float scale = rsqrtf(stot * (1.f / D_INNER) + EPS_F);
  unsigned short o16[16];
#pragma unroll
  for (int i = 0; i < 16; i++) o16[i] = f2bf(g[i] * scale * norm_w[c0 + i]);
  *(uint4*)&ybf[base] = *(uint4*)&o16[0];
  *(uint4*)&ybf[base + 8] = *(uint4*)&o16[8];
}

extern "C" void kernel_launch(void* const* d_in, const int* in_sizes, int n_in,
                              void* d_out, int out_size, void* d_ws, size_t ws_size,
                              hipStream_t stream) {
  (void)in_sizes; (void)n_in; (void)out_size; (void)ws_size;
  const float* x          = (const float*)d_in[0];
  const float* in_proj_w  = (const float*)d_in[3];
  const float* conv_w     = (const float*)d_in[4];
  const float* conv_b     = (const float*)d_in[5];
  const float* dt_bias    = (const float*)d_in[6];
  const float* A_log      = (const float*)d_in[7];
  const float* Dskip      = (const float*)d_in[8];
  const float* norm_w     = (const float*)d_in[9];
  const float* out_proj_w = (const float*)d_in[10];
  float* out = (float*)d_out;

  // Workspace (overlays strictly write-after-last-read):
  //   zx 69,730,304 | xconv 33,554,432 | Bf/Cf 2x2,097,152 | dtv/la 2x1,048,576
  //   ca 1,048,576 | G 524,288 | Shin 67,108,864 (S -> hin in-place; also hosts
  //   xb@+0, wib@+16.7M pre-scan and ybf@+0, wob@+33.5M post-scan) | yp 33,554,432
  // total 211,812,352 B
  char* w = (char*)d_ws;
  unsigned short* zx    = (unsigned short*)(w);
  unsigned short* xconv = (unsigned short*)(w + 69730304);
  float* Bf  = (float*)(w + 103284736);
  float* Cf  = (float*)(w + 105381888);
  float* dtv = (float*)(w + 107479040);
  float* lav = (float*)(w + 108527616);
  float* ca  = (float*)(w + 109576192);
  unsigned short* G    = (unsigned short*)(w + 110624768);
  unsigned short* Shin = (unsigned short*)(w + 111149056);
  unsigned short* yp   = (unsigned short*)(w + 178257920);
  unsigned short* xb   = (unsigned short*)(w + 111149056);   // pre-scan overlay
  unsigned short* wib  = (unsigned short*)(w + 127926272);   // pre-scan overlay
  unsigned short* ybf  = (unsigned short*)(w + 111149056);   // post-scan overlay
  unsigned short* wob  = (unsigned short*)(w + 144703488);   // post-scan overlay

  cast_kernel<<<BT * D_MODEL / 8 / 256, 256, 0, stream>>>(x, xb, BT * D_MODEL);
  cast_kernel<<<D_IN_PROJ * D_MODEL / 8 / 256, 256, 0, stream>>>(in_proj_w, wib, D_IN_PROJ * D_MODEL);
  gemm_tn_kernel<false><<<dim3((D_IN_PROJ + 127) / 128, BT / 128), 256, 0, stream>>>(
      xb, wib, zx, BT, D_IN_PROJ, D_MODEL);
  conv_silu_kernel<<<(BT * (CONV_DIM / 8) + 255) / 256, 256, 0, stream>>>(
      zx, conv_w, conv_b, xconv, Bf, Cf);
  dt_prep_kernel<<<(BT * NHEADS) / 256, 256, 0, stream>>>(zx, dt_bias, A_log, dtv, lav);
  cumsum_kernel<<<BB * NCHUNK * NHEADS / 4, 256, 0, stream>>>(lav, ca);
  chunk_g_kernel<<<BB * NCHUNK, 256, 0, stream>>>(Bf, Cf, G);
  chunk_state_kernel<<<BB * NHEADS * NCHUNK, 256, 0, stream>>>(Bf, xconv, dtv, ca, Shin);
  state_pass_kernel<<<BB * NHEADS * 8, 256, 0, stream>>>(Shin, ca);
  chunk_y_kernel<<<BB * NHEADS * NCHUNK, 256, 0, stream>>>(G, Cf, xconv, dtv, ca, Shin, Dskip, yp);
  gate_norm_kernel<<<BT, 256, 0, stream>>>(yp, zx, norm_w, ybf);
  cast_kernel<<<D_MODEL * D_INNER / 8 / 256, 256, 0, stream>>>(out_proj_w, wob, D_MODEL * D_INNER);
  gemm_tn_kernel<true><<<dim3(D_MODEL / 128, BT / 128), 256, 0, stream>>>(
      ybf, wob, out, BT, D_MODEL, D_INNER);
}

// Round 4
// 614.411 us; speedup vs baseline: 1.9381x; 1.0916x over previous
//
#include <hip/hip_runtime.h>

#define D_MODEL 2048
#define D_INNER 4096
#define D_STATE 128
#define HEADDIM 64
#define NHEADS 64
#define CONV_DIM 4352
#define D_IN_PROJ 8512
#define BB 2
#define TSEQ 2048
#define BT (BB*TSEQ)
#define NCHUNK 32
#define LCH 64
#define EPS_F 1e-5f

typedef __bf16 bf16x8 __attribute__((ext_vector_type(8)));
typedef float f32x4 __attribute__((ext_vector_type(4)));

__device__ __forceinline__ float bf2f(unsigned short u){
  unsigned int x = ((unsigned int)u) << 16;
  return __builtin_bit_cast(float, x);
}
__device__ __forceinline__ unsigned short f2bf(float f){
  unsigned int x = __builtin_bit_cast(unsigned int, f);
  x += 0x7fffu + ((x >> 16) & 1u);
  return (unsigned short)(x >> 16);
}

// async global->LDS, 16 B/lane: LDS dest = wave-uniform base + lane*16.
__device__ __forceinline__ void async_copy16(const unsigned short* g, unsigned short* l) {
  __builtin_amdgcn_global_load_lds(
      (const __attribute__((address_space(1))) unsigned int*)g,
      (__attribute__((address_space(3))) unsigned int*)l, 16, 0, 0);
}

// fp32 -> bf16 cast, 8 elems/thread. n % 8 == 0.
__global__ __launch_bounds__(256) void cast_kernel(
    const float* __restrict__ in, unsigned short* __restrict__ out, int n)
{
  int i = (blockIdx.x * 256 + threadIdx.x) * 8;
  if (i >= n) return;
  float4 a = *(const float4*)&in[i];
  float4 b = *(const float4*)&in[i + 4];
  unsigned short o[8] = { f2bf(a.x), f2bf(a.y), f2bf(a.z), f2bf(a.w),
                          f2bf(b.x), f2bf(b.y), f2bf(b.z), f2bf(b.w) };
  *(uint4*)&out[i] = *(uint4*)o;
}

// C[m,n] = sum_k A[m,k]*B[n,k]; A: MxK bf16, B: NxK bf16 (row-major).
// m97-style: global_load_lds width-16 staging, unpadded LDS + XOR-8 swizzle,
// band-swizzled 1-D grid (8 N-tiles x all M-tiles per band) for L2 locality.
// NT = ceil(N/128), MT = M/128. B-tile rows >= N are read (in-workspace OOB,
// garbage confined to cols >= N per-column in MFMA) and masked at store.
template <bool F32OUT>
__global__ __launch_bounds__(256) void gemm_tn_kernel(
    const unsigned short* __restrict__ A, const unsigned short* __restrict__ Bm,
    void* __restrict__ Cout, int M, int N, int K, int NT, int MT)
{
  __shared__ __align__(16) unsigned short As[128 * 64];
  __shared__ __align__(16) unsigned short Bs[128 * 64];
  int tid = threadIdx.x;

  // band swizzle: consecutive 8 blocks share an A-tile (one per XCD);
  // within a band each XCD walks all M-tiles against one B-column -> L2 reuse.
  int bid = blockIdx.x;
  int fullBands = NT >> 3;
  int blocksFull = fullBands * 8 * MT;
  int mt, nt;
  if (bid < blocksFull) {
    int band = bid / (8 * MT);
    int wI = bid - band * (8 * MT);
    nt = band * 8 + (wI & 7);
    mt = wI >> 3;
  } else {
    int rem = bid - blocksFull;
    int WL = NT - fullBands * 8;
    nt = fullBands * 8 + rem % WL;
    mt = rem / WL;
  }
  int m0 = mt * 128, n0 = nt * 128;

  int wave = tid >> 6, lane = tid & 63;
  int wm = wave >> 1, wn = wave & 1;           // 2x2 wave grid, 64x64 per wave
  int lm = lane & 15, kqb = lane >> 4;         // frag: m/n = lane&15, k-block = lane>>4
  int sw = lm & 7;                             // per-lane LDS xor swizzle

  // staging: wave stages A rows [wave*32,+32) and B rows [wave*32,+32),
  // 4 instrs each (8 rows/instr). lane: row = lr, src block = lc ^ lr.
  int lr = lane >> 3, lc = lane & 7, bg = lc ^ lr;
  const unsigned short* Ap = A + (size_t)(m0 + wave * 32 + lr) * K + bg * 8;
  const unsigned short* Bp = Bm + (size_t)(n0 + wave * 32 + lr) * K + bg * 8;

  f32x4 acc[4][4] = {};

  for (int k0 = 0; k0 < K; k0 += 64) {
#pragma unroll
    for (int q = 0; q < 4; q++) {
      async_copy16(Ap + (size_t)q * 8 * K + k0, &As[(wave * 32 + q * 8) * 64]);
      async_copy16(Bp + (size_t)q * 8 * K + k0, &Bs[(wave * 32 + q * 8) * 64]);
    }
    __syncthreads();   // drains vmcnt(0): LDS tiles ready
#pragma unroll
    for (int kk = 0; kk < 64; kk += 32) {
      int b0 = (kk >> 3) + kqb;
      int boff = (b0 ^ sw) * 8;
      bf16x8 af[4], bfr[4];
#pragma unroll
      for (int i = 0; i < 4; i++) af[i]  = *(const bf16x8*)&As[(wm * 64 + i * 16 + lm) * 64 + boff];
#pragma unroll
      for (int j = 0; j < 4; j++) bfr[j] = *(const bf16x8*)&Bs[(wn * 64 + j * 16 + lm) * 64 + boff];
#pragma unroll
      for (int i = 0; i < 4; i++)
#pragma unroll
        for (int j = 0; j < 4; j++)
          acc[i][j] = __builtin_amdgcn_mfma_f32_16x16x32_bf16(af[i], bfr[j], acc[i][j], 0, 0, 0);
    }
    __syncthreads();   // all waves done reading before next overwrite
  }

  // C/D layout: col = lane&15 (n), row = (lane>>4)*4 + reg (m)
  int rq = lane >> 4;
#pragma unroll
  for (int i = 0; i < 4; i++) {
#pragma unroll
    for (int j = 0; j < 4; j++) {
      int col = n0 + wn * 64 + j * 16 + lm;
      if (col < N) {
        int mrow = m0 + wm * 64 + i * 16 + rq * 4;
#pragma unroll
        for (int r = 0; r < 4; r++) {
          if (F32OUT) ((float*)Cout)[(size_t)(mrow + r) * N + col] = acc[i][j][r];
          else ((unsigned short*)Cout)[(size_t)(mrow + r) * N + col] = f2bf(acc[i][j][r]);
        }
      }
    }
  }
}

// Depthwise causal conv (window 4) + bias + silu.
__global__ __launch_bounds__(256) void conv_silu_kernel(
    const unsigned short* __restrict__ zx, const float* __restrict__ conv_w,
    const float* __restrict__ conv_b,
    unsigned short* __restrict__ xconv, float* __restrict__ Bf, float* __restrict__ Cf)
{
  const int NG = CONV_DIM / 8;
  int gid = blockIdx.x * 256 + threadIdx.x;
  if (gid >= BT * NG) return;
  int cg = gid % NG; int bt = gid / NG;
  int t = bt % TSEQ;
  int c0 = cg * 8;

  float wgt[8][4];
#pragma unroll
  for (int i = 0; i < 8; i++)
#pragma unroll
    for (int k = 0; k < 4; k++) wgt[i][k] = conv_w[(c0 + i) * 4 + k];

  float acc[8];
#pragma unroll
  for (int i = 0; i < 8; i++) acc[i] = conv_b[c0 + i];

#pragma unroll
  for (int k = 0; k < 4; k++) {
    int ts = t - 3 + k;
    if (ts < 0) continue;
    unsigned short xv[8];
    *(uint4*)xv = *(const uint4*)&zx[(size_t)(bt - 3 + k) * D_IN_PROJ + D_INNER + c0];
#pragma unroll
    for (int i = 0; i < 8; i++) acc[i] = fmaf(bf2f(xv[i]), wgt[i][k], acc[i]);
  }

  if (c0 < D_INNER) {
    unsigned short o[8];
#pragma unroll
    for (int i = 0; i < 8; i++) { float v = acc[i]; v = v / (1.f + expf(-v)); o[i] = f2bf(v); }
    *(uint4*)&xconv[(size_t)bt * D_INNER + c0] = *(uint4*)o;
  } else if (c0 < D_INNER + D_STATE) {
    int n = c0 - D_INNER;
#pragma unroll
    for (int i = 0; i < 8; i++) { float v = acc[i]; Bf[(size_t)bt * D_STATE + n + i] = v / (1.f + expf(-v)); }
  } else {
    int n = c0 - D_INNER - D_STATE;
#pragma unroll
    for (int i = 0; i < 8; i++) { float v = acc[i]; Cf[(size_t)bt * D_STATE + n + i] = v / (1.f + expf(-v)); }
  }
}

// dt = softplus(dt_raw + dt_bias); la = dt * A  (A = -exp(A_log)); per (b,t,h)
__global__ __launch_bounds__(256) void dt_prep_kernel(
    const unsigned short* __restrict__ zx, const float* __restrict__ dt_bias,
    const float* __restrict__ A_log, float* __restrict__ dtv, float* __restrict__ lav)
{
  int gid = blockIdx.x * 256 + threadIdx.x;  // bt*64 + h
  int h = gid & 63; int bt = gid >> 6;
  float x = bf2f(zx[(size_t)bt * D_IN_PROJ + D_INNER + CONV_DIM + h]) + dt_bias[h];
  float dt = (x > 20.f) ? x : log1pf(expf(x));
  float A = -expf(A_log[h]);
  dtv[gid] = dt;
  lav[gid] = dt * A;
}

// Inclusive cumsum of la within each chunk. One wave per (b,chunk,h).
__global__ __launch_bounds__(256) void cumsum_kernel(
    const float* __restrict__ lav, float* __restrict__ ca)
{
  int g = blockIdx.x * 4 + (threadIdx.x >> 6);   // g = (b*32+c)*64 + h
  int lane = threadIdx.x & 63;
  int h = g & 63; int cb = g >> 6;
  float v = lav[((size_t)cb * 64 + lane) * 64 + h];
#pragma unroll
  for (int off = 1; off < 64; off <<= 1) {
    float t = __shfl_up(v, off);
    if (lane >= off) v += t;
  }
  ca[(size_t)g * 64 + lane] = v;
}

// G[i,j] = sum_n C[i,n]*B[j,n] per (b,chunk). Shared across heads (NGROUPS=1).
__global__ __launch_bounds__(256) void chunk_g_kernel(
    const float* __restrict__ Bf, const float* __restrict__ Cf,
    unsigned short* __restrict__ G)
{
  __shared__ __align__(16) unsigned short Cs[64][136];
  __shared__ __align__(16) unsigned short Bs2[64][136];
  int tid = threadIdx.x; int cb = blockIdx.x;
  size_t bt0 = (size_t)cb * 64;
  int row = tid >> 2, seg = (tid & 3) * 32;
#pragma unroll
  for (int u = 0; u < 32; u += 8) {
    float4 a = *(const float4*)&Cf[(bt0 + row) * 128 + seg + u];
    float4 b = *(const float4*)&Cf[(bt0 + row) * 128 + seg + u + 4];
    unsigned short o[8] = { f2bf(a.x), f2bf(a.y), f2bf(a.z), f2bf(a.w),
                            f2bf(b.x), f2bf(b.y), f2bf(b.z), f2bf(b.w) };
    *(uint4*)&Cs[row][seg + u] = *(uint4*)o;
    float4 c = *(const float4*)&Bf[(bt0 + row) * 128 + seg + u];
    float4 d = *(const float4*)&Bf[(bt0 + row) * 128 + seg + u + 4];
    unsigned short o2[8] = { f2bf(c.x), f2bf(c.y), f2bf(c.z), f2bf(c.w),
                             f2bf(d.x), f2bf(d.y), f2bf(d.z), f2bf(d.w) };
    *(uint4*)&Bs2[row][seg + u] = *(uint4*)o2;
  }
  __syncthreads();
  int wave = tid >> 6, lane = tid & 63, lm = lane & 15, kq = (lane >> 4) * 8, rq = lane >> 4;
  f32x4 acc[4] = {};
#pragma unroll
  for (int ks = 0; ks < 4; ks++) {
    bf16x8 af = *(const bf16x8*)&Cs[wave * 16 + lm][ks * 32 + kq];
#pragma unroll
    for (int jt = 0; jt < 4; jt++) {
      bf16x8 bb = *(const bf16x8*)&Bs2[jt * 16 + lm][ks * 32 + kq];
      acc[jt] = __builtin_amdgcn_mfma_f32_16x16x32_bf16(af, bb, acc[jt], 0, 0, 0);
    }
  }
#pragma unroll
  for (int jt = 0; jt < 4; jt++)
#pragma unroll
    for (int r = 0; r < 4; r++) {
      int i = wave * 16 + rq * 4 + r, j = jt * 16 + lm;
      G[(size_t)cb * 4096 + i * 64 + j] = f2bf(acc[jt][r]);
    }
}

// S[p,n] = sum_j exp(ca63-ca[j])*dt[j]*x[j,p] * B[j,n], per (b,h,chunk).
__global__ __launch_bounds__(256) void chunk_state_kernel(
    const float* __restrict__ Bf, const unsigned short* __restrict__ xconv,
    const float* __restrict__ dtv, const float* __restrict__ ca,
    unsigned short* __restrict__ S)
{
  __shared__ __align__(16) unsigned short Ax[64][72];
  __shared__ __align__(16) unsigned short Bn[128][72];
  int tid = threadIdx.x;
  int c = blockIdx.x & 31, h = (blockIdx.x >> 5) & 63, b = blockIdx.x >> 11;
  int cb = b * 32 + c;
  size_t bt0 = (size_t)cb * 64;
  const float* cag = &ca[((size_t)cb * 64 + h) * 64];
  float ca63 = cag[63];
  {
    int j = tid >> 2, pseg = (tid & 3) * 16;
    float wj = expf(ca63 - cag[j]) * dtv[(bt0 + j) * 64 + h];
    unsigned short xv[16];
    *(uint4*)&xv[0] = *(const uint4*)&xconv[(bt0 + j) * 4096 + h * 64 + pseg];
    *(uint4*)&xv[8] = *(const uint4*)&xconv[(bt0 + j) * 4096 + h * 64 + pseg + 8];
#pragma unroll
    for (int q = 0; q < 16; q++) Ax[pseg + q][j] = f2bf(wj * bf2f(xv[q]));
  }
  {
    int j = tid >> 2, nseg = (tid & 3) * 32;
#pragma unroll
    for (int u = 0; u < 32; u += 4) {
      float4 bv = *(const float4*)&Bf[(bt0 + j) * 128 + nseg + u];
      Bn[nseg + u][j] = f2bf(bv.x); Bn[nseg + u + 1][j] = f2bf(bv.y);
      Bn[nseg + u + 2][j] = f2bf(bv.z); Bn[nseg + u + 3][j] = f2bf(bv.w);
    }
  }
  __syncthreads();
  int wave = tid >> 6, lane = tid & 63, lm = lane & 15, kq = (lane >> 4) * 8, rq = lane >> 4;
  f32x4 acc[8] = {};
#pragma unroll
  for (int ks = 0; ks < 2; ks++) {
    bf16x8 af = *(const bf16x8*)&Ax[wave * 16 + lm][ks * 32 + kq];
#pragma unroll
    for (int nt = 0; nt < 8; nt++) {
      bf16x8 bb = *(const bf16x8*)&Bn[nt * 16 + lm][ks * 32 + kq];
      acc[nt] = __builtin_amdgcn_mfma_f32_16x16x32_bf16(af, bb, acc[nt], 0, 0, 0);
    }
  }
  size_t sbase = ((size_t)(b * 64 + h) * 32 + c) * 8192;
#pragma unroll
  for (int nt = 0; nt < 8; nt++)
#pragma unroll
    for (int r = 0; r < 4; r++) {
      int p = wave * 16 + rq * 4 + r, n = nt * 16 + lm;
      S[sbase + p * 128 + n] = f2bf(acc[nt][r]);
    }
}

// Sequential pass over 32 chunks: read S[c], write h_in[c] (in place), update
// h = exp(ca63_c)*h + S[c]. Per (b,h); thread owns 4 state elems.
__global__ __launch_bounds__(256) void state_pass_kernel(
    unsigned short* __restrict__ Shin, const float* __restrict__ ca)
{
  int part = blockIdx.x & 7, bh = blockIdx.x >> 3;   // bh = b*64+h
  int h = bh & 63, b = bh >> 6;
  int e0 = part * 1024 + threadIdx.x * 4;
  size_t base = (size_t)bh * 32 * 8192;
  float hc[4] = {0.f, 0.f, 0.f, 0.f};
  for (int c = 0; c < 32; c++) {
    float sc = expf(ca[(((size_t)(b * 32 + c)) * 64 + h) * 64 + 63]);
    size_t off = base + (size_t)c * 8192 + e0;
    uint2 sv = *(uint2*)&Shin[off];
    unsigned short* sp = (unsigned short*)&sv;
    unsigned short ho[4];
#pragma unroll
    for (int q = 0; q < 4; q++) ho[q] = f2bf(hc[q]);
    *(uint2*)&Shin[off] = *(uint2*)ho;
#pragma unroll
    for (int q = 0; q < 4; q++) hc[q] = sc * hc[q] + bf2f(sp[q]);
  }
}

// y[i,p] = sum_j M[i,j]*dtx[j,p] + sum_n exp(ca[i])*C[i,n]*hin[p,n] + Dskip*x
// as one K=192 MFMA per (b,h,chunk). M[i,j] = G[i,j]*exp(ca[i]-ca[j]) (j<=i).
__global__ __launch_bounds__(256) void chunk_y_kernel(
    const unsigned short* __restrict__ G, const float* __restrict__ Cf,
    const unsigned short* __restrict__ xconv, const float* __restrict__ dtv,
    const float* __restrict__ ca, const unsigned short* __restrict__ hin,
    const float* __restrict__ Dskip, unsigned short* __restrict__ yp)
{
  __shared__ __align__(16) unsigned short Aop[64][200];
  __shared__ __align__(16) unsigned short Bop[64][200];
  __shared__ __align__(16) unsigned short xs[64][72];
  __shared__ float cas[64]; __shared__ float dts[64];
  int tid = threadIdx.x;
  int c = blockIdx.x & 31, h = (blockIdx.x >> 5) & 63, b = blockIdx.x >> 11;
  int cb = b * 32 + c;
  size_t bt0 = (size_t)cb * 64;
  if (tid < 64) {
    cas[tid] = ca[((size_t)cb * 64 + h) * 64 + tid];
    dts[tid] = dtv[(bt0 + tid) * 64 + h];
  }
  __syncthreads();
  {
    int i = tid >> 2, jseg = (tid & 3) * 16;
    float cai = cas[i];
    unsigned short gv[16];
    *(uint4*)&gv[0] = *(const uint4*)&G[(size_t)cb * 4096 + i * 64 + jseg];
    *(uint4*)&gv[8] = *(const uint4*)&G[(size_t)cb * 4096 + i * 64 + jseg + 8];
    unsigned short o[16];
#pragma unroll
    for (int q = 0; q < 16; q++) {
      int j = jseg + q;
      float m = (j <= i) ? bf2f(gv[q]) * expf(cai - cas[j]) : 0.f;
      o[q] = f2bf(m);
    }
    *(uint4*)&Aop[i][jseg] = *(uint4*)&o[0];
    *(uint4*)&Aop[i][jseg + 8] = *(uint4*)&o[8];
  }
  {
    int i = tid >> 2, nseg = (tid & 3) * 32;
    float sci = expf(cas[i]);
#pragma unroll
    for (int u = 0; u < 32; u += 8) {
      float4 a = *(const float4*)&Cf[(bt0 + i) * 128 + nseg + u];
      float4 bq = *(const float4*)&Cf[(bt0 + i) * 128 + nseg + u + 4];
      unsigned short o[8] = { f2bf(sci * a.x), f2bf(sci * a.y), f2bf(sci * a.z), f2bf(sci * a.w),
                              f2bf(sci * bq.x), f2bf(sci * bq.y), f2bf(sci * bq.z), f2bf(sci * bq.w) };
      *(uint4*)&Aop[i][64 + nseg + u] = *(uint4*)o;
    }
  }
  {
    int j = tid >> 2, pseg = (tid & 3) * 16;
    float dtj = dts[j];
    unsigned short xv[16];
    *(uint4*)&xv[0] = *(const uint4*)&xconv[(bt0 + j) * 4096 + h * 64 + pseg];
    *(uint4*)&xv[8] = *(const uint4*)&xconv[(bt0 + j) * 4096 + h * 64 + pseg + 8];
#pragma unroll
    for (int q = 0; q < 16; q++) Bop[pseg + q][j] = f2bf(dtj * bf2f(xv[q]));
    *(uint4*)&xs[j][pseg] = *(uint4*)&xv[0];
    *(uint4*)&xs[j][pseg + 8] = *(uint4*)&xv[8];
  }
  {
    int p = tid >> 2, nseg = (tid & 3) * 32;
    size_t hb = ((size_t)(b * 64 + h) * 32 + c) * 8192 + p * 128 + nseg;
#pragma unroll
    for (int u = 0; u < 32; u += 8)
      *(uint4*)&Bop[p][64 + nseg + u] = *(const uint4*)&hin[hb + u];
  }
  __syncthreads();
  int wave = tid >> 6, lane = tid & 63, lm = lane & 15, kq = (lane >> 4) * 8, rq = lane >> 4;
  f32x4 acc[4] = {};
#pragma unroll
  for (int ks = 0; ks < 6; ks++) {
    bf16x8 af = *(const bf16x8*)&Aop[wave * 16 + lm][ks * 32 + kq];
#pragma unroll
    for (int pt = 0; pt < 4; pt++) {
      bf16x8 bb = *(const bf16x8*)&Bop[pt * 16 + lm][ks * 32 + kq];
      acc[pt] = __builtin_amdgcn_mfma_f32_16x16x32_bf16(af, bb, acc[pt], 0, 0, 0);
    }
  }
  float dsk = Dskip[h];
#pragma unroll
  for (int pt = 0; pt < 4; pt++)
#pragma unroll
    for (int r = 0; r < 4; r++) {
      int i = wave * 16 + rq * 4 + r, p = pt * 16 + lm;
      float y = acc[pt][r] + dsk * bf2f(xs[i][p]);
      yp[(bt0 + i) * 4096 + h * 64 + p] = f2bf(y);
    }
}

// y already includes Dskip*x. gate with silu(z), rmsnorm, write bf16.
__global__ __launch_bounds__(256) void gate_norm_kernel(
    const unsigned short* __restrict__ yp, const unsigned short* __restrict__ zx,
    const float* __restrict__ norm_w, unsigned short* __restrict__ ybf)
{
  int row = blockIdx.x; int tid = threadIdx.x;
  int c0 = tid * 16;
  unsigned short y0[16], zv[16];
  const size_t base = (size_t)row * D_INNER + c0;
  *(uint4*)&y0[0] = *(const uint4*)&yp[base];
  *(uint4*)&y0[8] = *(const uint4*)&yp[base + 8];
  const size_t zbase = (size_t)row * D_IN_PROJ + c0;
  *(uint4*)&zv[0] = *(const uint4*)&zx[zbase];
  *(uint4*)&zv[8] = *(const uint4*)&zx[zbase + 8];

  float g[16]; float ss = 0.f;
#pragma unroll
  for (int i = 0; i < 16; i++) {
    float y = bf2f(y0[i]);
    float z = bf2f(zv[i]);
    float gate = z / (1.f + expf(-z));
    float gv = y * gate;
    g[i] = gv; ss += gv * gv;
  }
#pragma unroll
  for (int o = 32; o >= 1; o >>= 1) ss += __shfl_xor(ss, o);
  __shared__ float red[4]; __shared__ float stot;
  if ((tid & 63) == 0) red[tid >> 6] = ss;
  __syncthreads();
  if (tid == 0) stot = red[0] + red[1] + red[2] + red[3];
  __syncthreads();
  float scale = rsqrtf(stot * (1.f / D_INNER) + EPS_F);
  unsigned short o16[16];
#pragma unroll
  for (int i = 0; i < 16; i++) o16[i] = f2bf(g[i] * scale * norm_w[c0 + i]);
  *(uint4*)&ybf[base] = *(uint4*)&o16[0];
  *(uint4*)&ybf[base + 8] = *(uint4*)&o16[8];
}

extern "C" void kernel_launch(void* const* d_in, const int* in_sizes, int n_in,
                              void* d_out, int out_size, void* d_ws, size_t ws_size,
                              hipStream_t stream) {
  (void)in_sizes; (void)n_in; (void)out_size; (void)ws_size;
  const float* x          = (const float*)d_in[0];
  const float* in_proj_w  = (const float*)d_in[3];
  const float* conv_w     = (const float*)d_in[4];
  const float* conv_b     = (const float*)d_in[5];
  const float* dt_bias    = (const float*)d_in[6];
  const float* A_log      = (const float*)d_in[7];
  const float* Dskip      = (const float*)d_in[8];
  const float* norm_w     = (const float*)d_in[9];
  const float* out_proj_w = (const float*)d_in[10];
  float* out = (float*)d_out;

  char* w = (char*)d_ws;
  unsigned short* zx    = (unsigned short*)(w);
  unsigned short* xconv = (unsigned short*)(w + 69730304);
  float* Bf  = (float*)(w + 103284736);
  float* Cf  = (float*)(w + 105381888);
  float* dtv = (float*)(w + 107479040);
  float* lav = (float*)(w + 108527616);
  float* ca  = (float*)(w + 109576192);
  unsigned short* G    = (unsigned short*)(w + 110624768);
  unsigned short* Shin = (unsigned short*)(w + 111149056);
  unsigned short* yp   = (unsigned short*)(w + 178257920);
  unsigned short* xb   = (unsigned short*)(w + 111149056);   // pre-scan overlay
  unsigned short* wib  = (unsigned short*)(w + 127926272);   // pre-scan overlay
  unsigned short* ybf  = (unsigned short*)(w + 111149056);   // post-scan overlay
  unsigned short* wob  = (unsigned short*)(w + 144703488);   // post-scan overlay

  cast_kernel<<<BT * D_MODEL / 8 / 256, 256, 0, stream>>>(x, xb, BT * D_MODEL);
  cast_kernel<<<D_IN_PROJ * D_MODEL / 8 / 256, 256, 0, stream>>>(in_proj_w, wib, D_IN_PROJ * D_MODEL);
  {
    int NT = (D_IN_PROJ + 127) / 128, MT = BT / 128;
    gemm_tn_kernel<false><<<NT * MT, 256, 0, stream>>>(
        xb, wib, zx, BT, D_IN_PROJ, D_MODEL, NT, MT);
  }
  conv_silu_kernel<<<(BT * (CONV_DIM / 8) + 255) / 256, 256, 0, stream>>>(
      zx, conv_w, conv_b, xconv, Bf, Cf);
  dt_prep_kernel<<<(BT * NHEADS) / 256, 256, 0, stream>>>(zx, dt_bias, A_log, dtv, lav);
  cumsum_kernel<<<BB * NCHUNK * NHEADS / 4, 256, 0, stream>>>(lav, ca);
  chunk_g_kernel<<<BB * NCHUNK, 256, 0, stream>>>(Bf, Cf, G);
  chunk_state_kernel<<<BB * NHEADS * NCHUNK, 256, 0, stream>>>(Bf, xconv, dtv, ca, Shin);
  state_pass_kernel<<<BB * NHEADS * 8, 256, 0, stream>>>(Shin, ca);
  chunk_y_kernel<<<BB * NHEADS * NCHUNK, 256, 0, stream>>>(G, Cf, xconv, dtv, ca, Shin, Dskip, yp);
  gate_norm_kernel<<<BT, 256, 0, stream>>>(yp, zx, norm_w, ybf);
  cast_kernel<<<D_MODEL * D_INNER / 8 / 256, 256, 0, stream>>>(out_proj_w, wob, D_MODEL * D_INNER);
  {
    int NT = D_MODEL / 128, MT = BT / 128;
    gemm_tn_kernel<true><<<NT * MT, 256, 0, stream>>>(
        ybf, wob, out, BT, D_MODEL, D_INNER, NT, MT);
  }
}

// Round 5
// 602.821 us; speedup vs baseline: 1.9754x; 1.0192x over previous
//
#include <hip/hip_runtime.h>

#define D_MODEL 2048
#define D_INNER 4096
#define D_STATE 128
#define HEADDIM 64
#define NHEADS 64
#define CONV_DIM 4352
#define D_IN_PROJ 8512
#define BB 2
#define TSEQ 2048
#define BT (BB*TSEQ)
#define NCHUNK 32
#define LCH 64
#define EPS_F 1e-5f

typedef __bf16 bf16x8 __attribute__((ext_vector_type(8)));
typedef float f32x4 __attribute__((ext_vector_type(4)));

__device__ __forceinline__ float bf2f(unsigned short u){
  unsigned int x = ((unsigned int)u) << 16;
  return __builtin_bit_cast(float, x);
}
__device__ __forceinline__ unsigned short f2bf(float f){
  unsigned int x = __builtin_bit_cast(unsigned int, f);
  x += 0x7fffu + ((x >> 16) & 1u);
  return (unsigned short)(x >> 16);
}

// async global->LDS, 16 B/lane: LDS dest = wave-uniform base + lane*16.
__device__ __forceinline__ void async_copy16(const unsigned short* g, unsigned short* l) {
  __builtin_amdgcn_global_load_lds(
      (const __attribute__((address_space(1))) unsigned int*)g,
      (__attribute__((address_space(3))) unsigned int*)l, 16, 0, 0);
}

// fp32 -> bf16 cast, 8 elems/thread. n % 8 == 0.
__global__ __launch_bounds__(256) void cast_kernel(
    const float* __restrict__ in, unsigned short* __restrict__ out, int n)
{
  int i = (blockIdx.x * 256 + threadIdx.x) * 8;
  if (i >= n) return;
  float4 a = *(const float4*)&in[i];
  float4 b = *(const float4*)&in[i + 4];
  unsigned short o[8] = { f2bf(a.x), f2bf(a.y), f2bf(a.z), f2bf(a.w),
                          f2bf(b.x), f2bf(b.y), f2bf(b.z), f2bf(b.w) };
  *(uint4*)&out[i] = *(uint4*)o;
}

// C[m,n] = sum_k A[m,k]*B[n,k]; m97-style staging, XOR-8 LDS swizzle,
// band-swizzled grid. Unchanged from R4 (at its structural plateau).
template <bool F32OUT>
__global__ __launch_bounds__(256) void gemm_tn_kernel(
    const unsigned short* __restrict__ A, const unsigned short* __restrict__ Bm,
    void* __restrict__ Cout, int M, int N, int K, int NT, int MT)
{
  __shared__ __align__(16) unsigned short As[128 * 64];
  __shared__ __align__(16) unsigned short Bs[128 * 64];
  int tid = threadIdx.x;

  int bid = blockIdx.x;
  int fullBands = NT >> 3;
  int blocksFull = fullBands * 8 * MT;
  int mt, nt;
  if (bid < blocksFull) {
    int band = bid / (8 * MT);
    int wI = bid - band * (8 * MT);
    nt = band * 8 + (wI & 7);
    mt = wI >> 3;
  } else {
    int rem = bid - blocksFull;
    int WL = NT - fullBands * 8;
    nt = fullBands * 8 + rem % WL;
    mt = rem / WL;
  }
  int m0 = mt * 128, n0 = nt * 128;

  int wave = tid >> 6, lane = tid & 63;
  int wm = wave >> 1, wn = wave & 1;
  int lm = lane & 15, kqb = lane >> 4;
  int sw = lm & 7;

  int lr = lane >> 3, lc = lane & 7, bg = lc ^ lr;
  const unsigned short* Ap = A + (size_t)(m0 + wave * 32 + lr) * K + bg * 8;
  const unsigned short* Bp = Bm + (size_t)(n0 + wave * 32 + lr) * K + bg * 8;

  f32x4 acc[4][4] = {};

  for (int k0 = 0; k0 < K; k0 += 64) {
#pragma unroll
    for (int q = 0; q < 4; q++) {
      async_copy16(Ap + (size_t)q * 8 * K + k0, &As[(wave * 32 + q * 8) * 64]);
      async_copy16(Bp + (size_t)q * 8 * K + k0, &Bs[(wave * 32 + q * 8) * 64]);
    }
    __syncthreads();
#pragma unroll
    for (int kk = 0; kk < 64; kk += 32) {
      int b0 = (kk >> 3) + kqb;
      int boff = (b0 ^ sw) * 8;
      bf16x8 af[4], bfr[4];
#pragma unroll
      for (int i = 0; i < 4; i++) af[i]  = *(const bf16x8*)&As[(wm * 64 + i * 16 + lm) * 64 + boff];
#pragma unroll
      for (int j = 0; j < 4; j++) bfr[j] = *(const bf16x8*)&Bs[(wn * 64 + j * 16 + lm) * 64 + boff];
#pragma unroll
      for (int i = 0; i < 4; i++)
#pragma unroll
        for (int j = 0; j < 4; j++)
          acc[i][j] = __builtin_amdgcn_mfma_f32_16x16x32_bf16(af[i], bfr[j], acc[i][j], 0, 0, 0);
    }
    __syncthreads();
  }

  int rq = lane >> 4;
#pragma unroll
  for (int i = 0; i < 4; i++) {
#pragma unroll
    for (int j = 0; j < 4; j++) {
      int col = n0 + wn * 64 + j * 16 + lm;
      if (col < N) {
        int mrow = m0 + wm * 64 + i * 16 + rq * 4;
#pragma unroll
        for (int r = 0; r < 4; r++) {
          if (F32OUT) ((float*)Cout)[(size_t)(mrow + r) * N + col] = acc[i][j][r];
          else ((unsigned short*)Cout)[(size_t)(mrow + r) * N + col] = f2bf(acc[i][j][r]);
        }
      }
    }
  }
}

// Depthwise causal conv (window 4) + bias + silu. B/C now stored bf16.
__global__ __launch_bounds__(256) void conv_silu_kernel(
    const unsigned short* __restrict__ zx, const float* __restrict__ conv_w,
    const float* __restrict__ conv_b, unsigned short* __restrict__ xconv,
    unsigned short* __restrict__ Bbf, unsigned short* __restrict__ Cbf)
{
  const int NG = CONV_DIM / 8;
  int gid = blockIdx.x * 256 + threadIdx.x;
  if (gid >= BT * NG) return;
  int cg = gid % NG; int bt = gid / NG;
  int t = bt % TSEQ;
  int c0 = cg * 8;

  float wgt[8][4];
#pragma unroll
  for (int i = 0; i < 8; i++)
#pragma unroll
    for (int k = 0; k < 4; k++) wgt[i][k] = conv_w[(c0 + i) * 4 + k];

  float acc[8];
#pragma unroll
  for (int i = 0; i < 8; i++) acc[i] = conv_b[c0 + i];

#pragma unroll
  for (int k = 0; k < 4; k++) {
    int ts = t - 3 + k;
    if (ts < 0) continue;
    unsigned short xv[8];
    *(uint4*)xv = *(const uint4*)&zx[(size_t)(bt - 3 + k) * D_IN_PROJ + D_INNER + c0];
#pragma unroll
    for (int i = 0; i < 8; i++) acc[i] = fmaf(bf2f(xv[i]), wgt[i][k], acc[i]);
  }

  unsigned short o[8];
#pragma unroll
  for (int i = 0; i < 8; i++) { float v = acc[i]; o[i] = f2bf(v / (1.f + expf(-v))); }
  if (c0 < D_INNER) {
    *(uint4*)&xconv[(size_t)bt * D_INNER + c0] = *(uint4*)o;
  } else if (c0 < D_INNER + D_STATE) {
    *(uint4*)&Bbf[(size_t)bt * D_STATE + (c0 - D_INNER)] = *(uint4*)o;
  } else {
    *(uint4*)&Cbf[(size_t)bt * D_STATE + (c0 - D_INNER - D_STATE)] = *(uint4*)o;
  }
}

// Fused: dt = softplus(dt_raw + bias); la = dt*A; per-chunk inclusive cumsum.
// One wave per (cb,h); lane = t within chunk.
__global__ __launch_bounds__(256) void dtcum_kernel(
    const unsigned short* __restrict__ zx, const float* __restrict__ dt_bias,
    const float* __restrict__ A_log, float* __restrict__ dtv, float* __restrict__ ca)
{
  int g = blockIdx.x * 4 + (threadIdx.x >> 6);   // g = cb*64 + h
  int lane = threadIdx.x & 63;
  int h = g & 63; int cb = g >> 6;
  size_t bt = (size_t)cb * 64 + lane;
  float xr = bf2f(zx[bt * D_IN_PROJ + D_INNER + CONV_DIM + h]) + dt_bias[h];
  float dt = (xr > 20.f) ? xr : log1pf(expf(xr));
  float v = dt * (-expf(A_log[h]));
#pragma unroll
  for (int off = 1; off < 64; off <<= 1) {
    float t = __shfl_up(v, off);
    if (lane >= off) v += t;
  }
  dtv[bt * NHEADS + h] = dt;
  ca[(size_t)g * 64 + lane] = v;
}

// G[i,j] = sum_n C[i,n]*B[j,n] per (b,chunk). Shared across heads (NGROUPS=1).
__global__ __launch_bounds__(256) void chunk_g_kernel(
    const unsigned short* __restrict__ Bbf, const unsigned short* __restrict__ Cbf,
    unsigned short* __restrict__ G)
{
  __shared__ __align__(16) unsigned short Cs[64][136];
  __shared__ __align__(16) unsigned short Bs2[64][136];
  int tid = threadIdx.x; int cb = blockIdx.x;
  size_t bt0 = (size_t)cb * 64;
  int row = tid >> 2, seg = (tid & 3) * 32;
#pragma unroll
  for (int u = 0; u < 32; u += 8) {
    *(uint4*)&Cs[row][seg + u]  = *(const uint4*)&Cbf[(bt0 + row) * 128 + seg + u];
    *(uint4*)&Bs2[row][seg + u] = *(const uint4*)&Bbf[(bt0 + row) * 128 + seg + u];
  }
  __syncthreads();
  int wave = tid >> 6, lane = tid & 63, lm = lane & 15, kq = (lane >> 4) * 8, rq = lane >> 4;
  f32x4 acc[4] = {};
#pragma unroll
  for (int ks = 0; ks < 4; ks++) {
    bf16x8 af = *(const bf16x8*)&Cs[wave * 16 + lm][ks * 32 + kq];
#pragma unroll
    for (int jt = 0; jt < 4; jt++) {
      bf16x8 bb = *(const bf16x8*)&Bs2[jt * 16 + lm][ks * 32 + kq];
      acc[jt] = __builtin_amdgcn_mfma_f32_16x16x32_bf16(af, bb, acc[jt], 0, 0, 0);
    }
  }
#pragma unroll
  for (int jt = 0; jt < 4; jt++)
#pragma unroll
    for (int r = 0; r < 4; r++) {
      int i = wave * 16 + rq * 4 + r, j = jt * 16 + lm;
      G[(size_t)cb * 4096 + i * 64 + j] = f2bf(acc[jt][r]);
    }
}

// S[p,n] = sum_j exp(ca63-ca[j])*dt[j]*x[j,p] * B[j,n]. 4 heads per block:
// Bn (shared across heads) staged once; Ax restaged per head.
__global__ __launch_bounds__(256) void chunk_state_kernel(
    const unsigned short* __restrict__ Bbf, const unsigned short* __restrict__ xconv,
    const float* __restrict__ dtv, const float* __restrict__ ca,
    unsigned short* __restrict__ S)
{
  __shared__ __align__(16) unsigned short Ax[64][72];
  __shared__ __align__(16) unsigned short Bn[128][72];
  int tid = threadIdx.x;
  int c = blockIdx.x & 31, hb = (blockIdx.x >> 5) & 15, b = blockIdx.x >> 9;
  int cb = b * 32 + c;
  size_t bt0 = (size_t)cb * 64;
  {
    int j = tid >> 2, nseg = (tid & 3) * 32;
    unsigned short bv[32];
#pragma unroll
    for (int u = 0; u < 32; u += 8)
      *(uint4*)&bv[u] = *(const uint4*)&Bbf[(bt0 + j) * 128 + nseg + u];
#pragma unroll
    for (int u = 0; u < 32; u++) Bn[nseg + u][j] = bv[u];
  }
  int wave = tid >> 6, lane = tid & 63, lm = lane & 15, kq = (lane >> 4) * 8, rq = lane >> 4;
  int j = tid >> 2, pseg = (tid & 3) * 16;
  for (int hh = 0; hh < 4; hh++) {
    int h = hb * 4 + hh;
    const float* cag = &ca[((size_t)cb * 64 + h) * 64];
    float wj = expf(cag[63] - cag[j]) * dtv[(bt0 + j) * 64 + h];
    unsigned short xv[16];
    *(uint4*)&xv[0] = *(const uint4*)&xconv[(bt0 + j) * 4096 + h * 64 + pseg];
    *(uint4*)&xv[8] = *(const uint4*)&xconv[(bt0 + j) * 4096 + h * 64 + pseg + 8];
    if (hh) __syncthreads();           // prior iteration's reads complete
#pragma unroll
    for (int q = 0; q < 16; q++) Ax[pseg + q][j] = f2bf(wj * bf2f(xv[q]));
    __syncthreads();
    f32x4 acc[8] = {};
#pragma unroll
    for (int ks = 0; ks < 2; ks++) {
      bf16x8 af = *(const bf16x8*)&Ax[wave * 16 + lm][ks * 32 + kq];
#pragma unroll
      for (int nt = 0; nt < 8; nt++) {
        bf16x8 bb = *(const bf16x8*)&Bn[nt * 16 + lm][ks * 32 + kq];
        acc[nt] = __builtin_amdgcn_mfma_f32_16x16x32_bf16(af, bb, acc[nt], 0, 0, 0);
      }
    }
    size_t sbase = ((size_t)(b * 64 + h) * 32 + c) * 8192;
#pragma unroll
    for (int nt = 0; nt < 8; nt++)
#pragma unroll
      for (int r = 0; r < 4; r++) {
        int p = wave * 16 + rq * 4 + r, n = nt * 16 + lm;
        S[sbase + p * 128 + n] = f2bf(acc[nt][r]);
      }
  }
}

// Sequential pass over 32 chunks: read S[c], write h_in[c] in place,
// h = exp(ca63_c)*h + S[c]. Per (b,h); thread owns 4 state elems.
__global__ __launch_bounds__(256) void state_pass_kernel(
    unsigned short* __restrict__ Shin, const float* __restrict__ ca)
{
  int part = blockIdx.x & 7, bh = blockIdx.x >> 3;
  int h = bh & 63, b = bh >> 6;
  int e0 = part * 1024 + threadIdx.x * 4;
  size_t base = (size_t)bh * 32 * 8192;
  float hc[4] = {0.f, 0.f, 0.f, 0.f};
  for (int c = 0; c < 32; c++) {
    float sc = expf(ca[(((size_t)(b * 32 + c)) * 64 + h) * 64 + 63]);
    size_t off = base + (size_t)c * 8192 + e0;
    uint2 sv = *(uint2*)&Shin[off];
    unsigned short* sp = (unsigned short*)&sv;
    unsigned short ho[4];
#pragma unroll
    for (int q = 0; q < 4; q++) ho[q] = f2bf(hc[q]);
    *(uint2*)&Shin[off] = *(uint2*)ho;
#pragma unroll
    for (int q = 0; q < 4; q++) hc[q] = sc * hc[q] + bf2f(sp[q]);
  }
}

// y[i,p] = sum_j M'[i,j]*x[j,p] + sum_n (C[i,n]e^ca_i)*hin[p,n] + Dskip*x[i,p]
// with dt folded into M' = G*exp(ca_i-ca_j)*dt_j. One K=192 MFMA per (b,h,c).
__global__ __launch_bounds__(256) void chunk_y_kernel(
    const unsigned short* __restrict__ G, const unsigned short* __restrict__ Cbf,
    const unsigned short* __restrict__ xconv, const float* __restrict__ dtv,
    const float* __restrict__ ca, const unsigned short* __restrict__ hin,
    const float* __restrict__ Dskip, unsigned short* __restrict__ yp)
{
  __shared__ __align__(16) unsigned short Aop[64][200];
  __shared__ __align__(16) unsigned short Bop[64][200];
  __shared__ float cas[64]; __shared__ float dts[64];
  int tid = threadIdx.x;
  int c = blockIdx.x & 31, h = (blockIdx.x >> 5) & 63, b = blockIdx.x >> 11;
  int cb = b * 32 + c;
  size_t bt0 = (size_t)cb * 64;
  if (tid < 64) {
    cas[tid] = ca[((size_t)cb * 64 + h) * 64 + tid];
    dts[tid] = dtv[(bt0 + tid) * 64 + h];
  }
  __syncthreads();
  {
    int i = tid >> 2, jseg = (tid & 3) * 16;
    float cai = cas[i];
    unsigned short gv[16];
    *(uint4*)&gv[0] = *(const uint4*)&G[(size_t)cb * 4096 + i * 64 + jseg];
    *(uint4*)&gv[8] = *(const uint4*)&G[(size_t)cb * 4096 + i * 64 + jseg + 8];
    unsigned short o[16];
#pragma unroll
    for (int q = 0; q < 16; q++) {
      int j = jseg + q;
      float m = (j <= i) ? bf2f(gv[q]) * expf(cai - cas[j]) * dts[j] : 0.f;
      o[q] = f2bf(m);
    }
    *(uint4*)&Aop[i][jseg] = *(uint4*)&o[0];
    *(uint4*)&Aop[i][jseg + 8] = *(uint4*)&o[8];
  }
  {
    int i = tid >> 2, nseg = (tid & 3) * 32;
    float sci = expf(cas[i]);
#pragma unroll
    for (int u = 0; u < 32; u += 8) {
      unsigned short cv[8];
      *(uint4*)cv = *(const uint4*)&Cbf[(bt0 + i) * 128 + nseg + u];
      unsigned short o[8];
#pragma unroll
      for (int q = 0; q < 8; q++) o[q] = f2bf(sci * bf2f(cv[q]));
      *(uint4*)&Aop[i][64 + nseg + u] = *(uint4*)o;
    }
  }
  {
    int j = tid >> 2, pseg = (tid & 3) * 16;
    unsigned short xv[16];
    *(uint4*)&xv[0] = *(const uint4*)&xconv[(bt0 + j) * 4096 + h * 64 + pseg];
    *(uint4*)&xv[8] = *(const uint4*)&xconv[(bt0 + j) * 4096 + h * 64 + pseg + 8];
#pragma unroll
    for (int q = 0; q < 16; q++) Bop[pseg + q][j] = xv[q];
  }
  {
    int p = tid >> 2, nseg = (tid & 3) * 32;
    size_t hb = ((size_t)(b * 64 + h) * 32 + c) * 8192 + p * 128 + nseg;
#pragma unroll
    for (int u = 0; u < 32; u += 8)
      *(uint4*)&Bop[p][64 + nseg + u] = *(const uint4*)&hin[hb + u];
  }
  __syncthreads();
  int wave = tid >> 6, lane = tid & 63, lm = lane & 15, kq = (lane >> 4) * 8, rq = lane >> 4;
  f32x4 acc[4] = {};
#pragma unroll
  for (int ks = 0; ks < 6; ks++) {
    bf16x8 af = *(const bf16x8*)&Aop[wave * 16 + lm][ks * 32 + kq];
#pragma unroll
    for (int pt = 0; pt < 4; pt++) {
      bf16x8 bb = *(const bf16x8*)&Bop[pt * 16 + lm][ks * 32 + kq];
      acc[pt] = __builtin_amdgcn_mfma_f32_16x16x32_bf16(af, bb, acc[pt], 0, 0, 0);
    }
  }
  float dsk = Dskip[h];
#pragma unroll
  for (int pt = 0; pt < 4; pt++)
#pragma unroll
    for (int r = 0; r < 4; r++) {
      int i = wave * 16 + rq * 4 + r, p = pt * 16 + lm;
      float y = acc[pt][r] + dsk * bf2f(Bop[p][i]);   // Bop[p][i] = x[i,p]
      yp[(bt0 + i) * 4096 + h * 64 + p] = f2bf(y);
    }
}

// gate with silu(z), rmsnorm, write bf16.
__global__ __launch_bounds__(256) void gate_norm_kernel(
    const unsigned short* __restrict__ yp, const unsigned short* __restrict__ zx,
    const float* __restrict__ norm_w, unsigned short* __restrict__ ybf)
{
  int row = blockIdx.x; int tid = threadIdx.x;
  int c0 = tid * 16;
  unsigned short y0[16], zv[16];
  const size_t base = (size_t)row * D_INNER + c0;
  *(uint4*)&y0[0] = *(const uint4*)&yp[base];
  *(uint4*)&y0[8] = *(const uint4*)&yp[base + 8];
  const size_t zbase = (size_t)row * D_IN_PROJ + c0;
  *(uint4*)&zv[0] = *(const uint4*)&zx[zbase];
  *(uint4*)&zv[8] = *(const uint4*)&zx[zbase + 8];

  float g[16]; float ss = 0.f;
#pragma unroll
  for (int i = 0; i < 16; i++) {
    float y = bf2f(y0[i]);
    float z = bf2f(zv[i]);
    float gate = z / (1.f + expf(-z));
    float gv = y * gate;
    g[i] = gv; ss += gv * gv;
  }
#pragma unroll
  for (int o = 32; o >= 1; o >>= 1) ss += __shfl_xor(ss, o);
  __shared__ float red[4]; __shared__ float stot;
  if ((tid & 63) == 0) red[tid >> 6] = ss;
  __syncthreads();
  if (tid == 0) stot = red[0] + red[1] + red[2] + red[3];
  __syncthreads();
  float scale = rsqrtf(stot * (1.f / D_INNER) + EPS_F);
  unsigned short o16[16];
#pragma unroll
  for (int i = 0; i < 16; i++) o16[i] = f2bf(g[i] * scale * norm_w[c0 + i]);
  *(uint4*)&ybf[base] = *(uint4*)&o16[0];
  *(uint4*)&ybf[base + 8] = *(uint4*)&o16[8];
}

extern "C" void kernel_launch(void* const* d_in, const int* in_sizes, int n_in,
                              void* d_out, int out_size, void* d_ws, size_t ws_size,
                              hipStream_t stream) {
  (void)in_sizes; (void)n_in; (void)out_size; (void)ws_size;
  const float* x          = (const float*)d_in[0];
  const float* in_proj_w  = (const float*)d_in[3];
  const float* conv_w     = (const float*)d_in[4];
  const float* conv_b     = (const float*)d_in[5];
  const float* dt_bias    = (const float*)d_in[6];
  const float* A_log      = (const float*)d_in[7];
  const float* Dskip      = (const float*)d_in[8];
  const float* norm_w     = (const float*)d_in[9];
  const float* out_proj_w = (const float*)d_in[10];
  float* out = (float*)d_out;

  char* w = (char*)d_ws;
  unsigned short* zx    = (unsigned short*)(w);
  unsigned short* xconv = (unsigned short*)(w + 69730304);
  unsigned short* Bbf = (unsigned short*)(w + 103284736);   // BT*128 bf16
  unsigned short* Cbf = (unsigned short*)(w + 105381888);   // BT*128 bf16
  float* dtv = (float*)(w + 107479040);
  float* ca  = (float*)(w + 109576192);
  unsigned short* G    = (unsigned short*)(w + 110624768);
  unsigned short* Shin = (unsigned short*)(w + 111149056);
  unsigned short* yp   = (unsigned short*)(w + 178257920);
  unsigned short* xb   = (unsigned short*)(w + 111149056);   // pre-scan overlay
  unsigned short* wib  = (unsigned short*)(w + 127926272);   // pre-scan overlay
  unsigned short* ybf  = (unsigned short*)(w + 111149056);   // post-scan overlay
  unsigned short* wob  = (unsigned short*)(w + 144703488);   // post-scan overlay

  cast_kernel<<<BT * D_MODEL / 8 / 256, 256, 0, stream>>>(x, xb, BT * D_MODEL);
  cast_kernel<<<D_IN_PROJ * D_MODEL / 8 / 256, 256, 0, stream>>>(in_proj_w, wib, D_IN_PROJ * D_MODEL);
  {
    int NT = (D_IN_PROJ + 127) / 128, MT = BT / 128;
    gemm_tn_kernel<false><<<NT * MT, 256, 0, stream>>>(
        xb, wib, zx, BT, D_IN_PROJ, D_MODEL, NT, MT);
  }
  conv_silu_kernel<<<(BT * (CONV_DIM / 8) + 255) / 256, 256, 0, stream>>>(
      zx, conv_w, conv_b, xconv, Bbf, Cbf);
  dtcum_kernel<<<BB * NCHUNK * NHEADS / 4, 256, 0, stream>>>(zx, dt_bias, A_log, dtv, ca);
  chunk_g_kernel<<<BB * NCHUNK, 256, 0, stream>>>(Bbf, Cbf, G);
  chunk_state_kernel<<<BB * 16 * NCHUNK, 256, 0, stream>>>(Bbf, xconv, dtv, ca, Shin);
  state_pass_kernel<<<BB * NHEADS * 8, 256, 0, stream>>>(Shin, ca);
  chunk_y_kernel<<<BB * NHEADS * NCHUNK, 256, 0, stream>>>(G, Cbf, xconv, dtv, ca, Shin, Dskip, yp);
  gate_norm_kernel<<<BT, 256, 0, stream>>>(yp, zx, norm_w, ybf);
  cast_kernel<<<D_MODEL * D_INNER / 8 / 256, 256, 0, stream>>>(out_proj_w, wob, D_MODEL * D_INNER);
  {
    int NT = D_MODEL / 128, MT = BT / 128;
    gemm_tn_kernel<true><<<NT * MT, 256, 0, stream>>>(
        ybf, wob, out, BT, D_MODEL, D_INNER, NT, MT);
  }
}